// Round 11
// baseline (107.223 us; speedup 1.0000x reference)
//
#include <hip/hip_runtime.h>
#include <stdint.h>

#define NN 8192      // nodes
#define FF 512       // feature dim
#define HH 64        // hidden
#define CC 10        // classes
#define PAD 12       // padded channel stride (3x float4)
#define EE 262144    // edges
#define NTR 512      // train nodes
#define ALPHA_NS 0.2f

#define CAP 96u              // slots per dst row (Poisson(32); P(deg>96) ~ e^-38)
#define EMPTY 0xFFFFFFFFu
#define ROWS_PB 32           // rows per k_init block
#define SLOTS_PB ((NN*CAP)/256u)   // 3072 csrc2 slots cleared per k_init block
#define FB 64                // fixup blocks

__device__ __forceinline__ float dot4(float4 a, float4 b){
    return a.x*b.x + a.y*b.y + a.z*b.z + a.w*b.w;
}

// ---------------------------------------------------------------------------
// k_init: per-block independent. Clears csrc2 slice (uint4), computes v01
// redundantly in LDS, s_src/s_dst/FW for its 32 rows, local cvec, padded Db.
// ---------------------------------------------------------------------------
__global__ __launch_bounds__(1024) void k_init(
    const float* __restrict__ W, const float* __restrict__ a,
    const float* __restrict__ h, const float* __restrict__ feat,
    const float* __restrict__ W1, const int* __restrict__ idx_tr,
    const int* __restrict__ labels,
    uint32_t* __restrict__ csrc2,
    float* __restrict__ s_src, float* __restrict__ s_dst,
    float* __restrict__ FW, float* __restrict__ Db)
{
    __shared__ float v0l[FF];
    __shared__ float v1l[FF];
    __shared__ int chist[CC];
    __shared__ float cvecl[CC];
    __shared__ uint8_t lmark[ROWS_PB];

    const int tid = threadIdx.x;
    const int b   = blockIdx.x;
    const int rbase = b * ROWS_PB;

    {   // uint4 clear: 3072 slots = 768 uint4 per block
        uint4* c4 = (uint4*)(csrc2 + (uint32_t)b*SLOTS_PB);
        const uint4 ev = make_uint4(EMPTY, EMPTY, EMPTY, EMPTY);
        for (uint32_t i = tid; i < SLOTS_PB/4u; i += 1024) c4[i] = ev;
    }

    // v01 in LDS: threads 0..511 -> v0, 512..1023 -> v1
    {
        int f = tid & (FF-1);
        const float* av = (tid < FF) ? a : (a + HH);
        float acc = 0.f;
        for (int hh = 0; hh < HH; ++hh) acc += W[hh*FF + f] * av[hh];
        if (tid < FF) v0l[f] = acc; else v1l[f] = acc;
    }

    if (tid < ROWS_PB) lmark[tid] = 0;
    if (tid < CC) chist[tid] = 0;
    __syncthreads();
    if (tid < NTR){
        int node = idx_tr[tid];
        atomicAdd(&chist[labels[node]], 1);
        unsigned lr = (unsigned)(node - rbase);
        if (lr < (unsigned)ROWS_PB) lmark[lr] = 1;
    }
    __syncthreads();
    if (tid < CC) cvecl[tid] = (float)chist[tid] / (float)NTR;
    __syncthreads();

    // s-dots + FW: 16 waves x 2 rows
    {
        const int wid = tid >> 6, lane = tid & 63;
        const float4* v0 = (const float4*)v0l;
        const float4* v1 = (const float4*)v1l;
        #pragma unroll
        for (int rr = 0; rr < 2; ++rr){
            int row = rbase + wid*2 + rr;
            const float4* hr = (const float4*)(h + (size_t)row*FF);
            float4 x0 = hr[lane*2], x1 = hr[lane*2+1];
            float a0 = dot4(x0, v0[lane*2]) + dot4(x1, v0[lane*2+1]);
            float a1 = dot4(x0, v1[lane*2]) + dot4(x1, v1[lane*2+1]);
            #pragma unroll
            for (int off = 32; off >= 1; off >>= 1){
                a0 += __shfl_xor(a0, off);
                a1 += __shfl_xor(a1, off);
            }
            if (lane == 0){ s_src[row] = a0; s_dst[row] = a1; }

            const float4* fr = (const float4*)(feat + (size_t)row*FF);
            float4 f0 = fr[lane*2], f1 = fr[lane*2+1];
            float acc[CC];
            #pragma unroll
            for (int c = 0; c < CC; ++c){
                const float4* wr = (const float4*)(W1 + c*FF);
                acc[c] = dot4(f0, wr[lane*2]) + dot4(f1, wr[lane*2+1]);
            }
            #pragma unroll
            for (int c = 0; c < CC; ++c){
                float r = acc[c];
                #pragma unroll
                for (int off = 32; off >= 1; off >>= 1) r += __shfl_xor(r, off);
                acc[c] = r;
            }
            if (lane == 0){
                #pragma unroll
                for (int c = 0; c < CC; ++c) FW[row*PAD + c] = acc[c];
            }
        }
    }

    // padded Db for this block's 32 rows: 32*12 = 384 elements
    if (tid < ROWS_PB*PAD){
        int il = tid / PAD, c = tid - il*PAD;
        int row = rbase + il;
        float v = 0.f;
        if (c < CC && lmark[il]) v = ((labels[row] == c) ? 1.0f : 0.0f) - cvecl[c];
        Db[row*PAD + c] = v;
    }
}

// ---------------------------------------------------------------------------
// k_build: pure CAS dedup+placement, TWO edges per thread (int2 loads).
// Key = src in the dst row's 96 slots. No value stores, no atomicAdds.
// ---------------------------------------------------------------------------
__global__ void k_build(const int* __restrict__ ei, uint32_t* __restrict__ csrc2)
{
    int k = (blockIdx.x*256 + threadIdx.x)*2;
    int2 s2 = *(const int2*)(ei + k);
    int2 d2 = *(const int2*)(ei + EE + k);
    #pragma unroll
    for (int j = 0; j < 2; ++j){
        uint32_t src = (uint32_t)((j == 0) ? s2.x : s2.y);
        uint32_t dst = (uint32_t)((j == 0) ? d2.x : d2.y);
        uint32_t base = dst * CAP;
        uint32_t p = (uint32_t)(((uint64_t)(src * 2654435761u) * CAP) >> 32);
        for (uint32_t it = 0; it < CAP; ++it){
            uint32_t prev = atomicCAS(&csrc2[base + p], EMPTY, src);
            if (prev == EMPTY || prev == src) break;   // placed, or duplicate -> drop
            p = (p + 1u == CAP) ? 0u : p + 1u;
        }
    }
}

// ---------------------------------------------------------------------------
// k_fixup: 64 blocks x 1024 threads; 16-lane group per row, 2 rows per group.
// Compacts row slots into tabc while recomputing e = exp(leaky(s_src+s_dst)),
// accumulates s1 partials in LDS (no global atomics), writes cnt.
// ---------------------------------------------------------------------------
__global__ __launch_bounds__(1024) void k_fixup(
    const uint32_t* __restrict__ csrc2, const float* __restrict__ s_src,
    const float* __restrict__ s_dst, uint2* __restrict__ tabc,
    uint32_t* __restrict__ cnt, float* __restrict__ s1p)
{
    __shared__ float s1l[NN];    // 32 KB
    const int tid = threadIdx.x;
    const int b   = blockIdx.x;
    const int wid = tid >> 6, lane = tid & 63;
    const int g   = lane >> 4, l16 = lane & 15;

    for (int i = tid; i < NN; i += 1024) s1l[i] = 0.f;
    __syncthreads();

    #pragma unroll
    for (int rr = 0; rr < 2; ++rr){
        const int row = (((b*16 + wid)*4 + g)*2) + rr;   // 64*16*4*2 = 8192
        const uint32_t base = (uint32_t)row * CAP;
        const float sdst = s_dst[row];
        uint32_t running = 0;
        #pragma unroll
        for (int step = 0; step < 6; ++step){     // 6*16 = 96 = CAP
            uint32_t key = csrc2[base + step*16 + l16];
            bool valid = (key != EMPTY);
            uint64_t bal = __ballot(valid);
            uint32_t grp = (uint32_t)((bal >> (g*16)) & 0xFFFFull);
            uint32_t rank = (uint32_t)__popc(grp & ((1u << l16) - 1u));
            if (valid){
                float z = s_src[key] + sdst;
                z = (z >= 0.f) ? z : ALPHA_NS * z;
                float e = expf(z);
                tabc[base + running + rank] = make_uint2(key, __float_as_uint(e));
                atomicAdd(&s1l[key], e);          // LDS atomic
            }
            running += (uint32_t)__popc(grp);
        }
        if (l16 == 0) cnt[row] = running;
    }
    __syncthreads();
    for (int i = tid; i < NN; i += 1024) s1p[(size_t)b*NN + i] = s1l[i];
}

// ---------------------------------------------------------------------------
// k_s1red: thread per row. Reduce s1 partials; self-loop append for s1==0
// rows; write inv_s1 and uh1 = Db / s1 (padded).
// ---------------------------------------------------------------------------
__global__ __launch_bounds__(256) void k_s1red(
    const float* __restrict__ s1p, uint2* __restrict__ tabc,
    uint32_t* __restrict__ cnt, const float* __restrict__ Db,
    float* __restrict__ invs1, float* __restrict__ uh1)
{
    int row = blockIdx.x*256 + threadIdx.x;
    float s = 0.f;
    for (int b = 0; b < FB; ++b) s += s1p[(size_t)b*NN + row];
    if (s == 0.f){                       // zero out-degree -> self loop, e=1
        uint32_t c = cnt[row];
        tabc[(uint32_t)row*CAP + c] = make_uint2((uint32_t)row, __float_as_uint(1.0f));
        cnt[row] = c + 1u;
        s = 1.0f;
    }
    float inv = 1.0f / s;
    invs1[row] = inv;
    const float4* d4 = (const float4*)(Db + (size_t)row*PAD);
    float4* u4 = (float4*)(uh1 + (size_t)row*PAD);
    #pragma unroll
    for (int q = 0; q < 3; ++q){
        float4 v = d4[q];
        v.x *= inv; v.y *= inv; v.z *= inv; v.w *= inv;
        u4[q] = v;
    }
}

// ---------------------------------------------------------------------------
// k_spmv: 32-lane row groups (2 rows/wave), 3x float4 gathers on 12-padded
// u-hat. acc = sum e * uh_in[src]; u = acc + Db (+FW at t=7);
// non-final: store uh_out = u * inv_s1 (padded); final: store u dense.
// ---------------------------------------------------------------------------
__global__ __launch_bounds__(256) void k_spmv(
    const uint32_t* __restrict__ cnt, const uint2* __restrict__ tabc,
    const float* __restrict__ uh_in, const float* __restrict__ Db,
    const float* __restrict__ FW, const float* __restrict__ invs1,
    float* __restrict__ uout, int add_fw, int final_step)
{
    const int tid = threadIdx.x;
    const int wid = tid >> 6, lane = tid & 63;
    const int l32 = lane & 31;
    const int row = (blockIdx.x*4 + wid)*2 + (lane >> 5);   // 1024 blocks
    const uint2* tp = tabc + (uint32_t)row * CAP;
    const uint32_t n = cnt[row];

    float acc[PAD];
    #pragma unroll
    for (int c = 0; c < PAD; ++c) acc[c] = 0.f;
    for (uint32_t p = (uint32_t)l32; p < n; p += 32u){
        uint2 v = tp[p];
        float w = __uint_as_float(v.y);
        const float4* u4 = (const float4*)(uh_in + (size_t)v.x*PAD);
        float4 u0 = u4[0], u1 = u4[1], u2 = u4[2];
        acc[0] += w*u0.x; acc[1] += w*u0.y; acc[2]  += w*u0.z; acc[3]  += w*u0.w;
        acc[4] += w*u1.x; acc[5] += w*u1.y; acc[6]  += w*u1.z; acc[7]  += w*u1.w;
        acc[8] += w*u2.x; acc[9] += w*u2.y; acc[10] += w*u2.z; acc[11] += w*u2.w;
    }
    #pragma unroll
    for (int c = 0; c < PAD; ++c){
        float r = acc[c];
        #pragma unroll
        for (int off = 16; off >= 1; off >>= 1) r += __shfl_xor(r, off, 32);
        acc[c] = r;
    }
    // lane l32 handles channel l32 (only 0..PAD-1 active)
    float v = acc[0];
    #pragma unroll
    for (int c = 1; c < PAD; ++c) v = (l32 == c) ? acc[c] : v;
    if (l32 < CC){
        v += Db[row*PAD + l32];
        if (add_fw) v += FW[row*PAD + l32];
    } else {
        v = 0.f;
    }
    if (final_step){
        if (l32 < CC) uout[(size_t)row*CC + l32] = v;
    } else {
        v *= invs1[row];
        if (l32 < PAD) uout[(size_t)row*PAD + l32] = v;
    }
}

extern "C" void kernel_launch(void* const* d_in, const int* in_sizes, int n_in,
                              void* d_out, int out_size, void* d_ws, size_t ws_size,
                              hipStream_t stream){
    const float* h    = (const float*)d_in[0];
    const float* W    = (const float*)d_in[1];
    const float* a    = (const float*)d_in[2];
    const float* W1   = (const float*)d_in[3];
    const float* feat = (const float*)d_in[4];
    const int* ei     = (const int*)d_in[5];
    const int* idx_tr = (const int*)d_in[6];
    const int* labels = (const int*)d_in[7];
    float* out = (float*)d_out;

    char* wsp = (char*)d_ws;
    auto alloc = [&](size_t bytes)->void*{
        void* p = (void*)wsp;
        wsp += (bytes + 255) & ~(size_t)255;
        return p;
    };
    uint32_t* csrc2 = (uint32_t*)alloc((size_t)NN*CAP*4);   // 3 MB
    uint2*    tabc  = (uint2*)   alloc((size_t)NN*CAP*8);   // 6 MB
    float*    s1p   = (float*)   alloc((size_t)FB*NN*4);    // 2 MB
    uint32_t* cnt   = (uint32_t*)alloc(NN*4);
    float*    invs1 = (float*)   alloc(NN*4);
    float*    s_src = (float*)   alloc(NN*4);
    float*    s_dst = (float*)   alloc(NN*4);
    float*    FW    = (float*)   alloc((size_t)NN*PAD*4);
    float*    Db    = (float*)   alloc((size_t)NN*PAD*4);
    float*    uA    = (float*)   alloc((size_t)NN*PAD*4);
    float*    uB    = (float*)   alloc((size_t)NN*PAD*4);

    k_init <<<256, 1024, 0, stream>>>(W, a, h, feat, W1, idx_tr, labels,
                                      csrc2, s_src, s_dst, FW, Db);
    k_build<<<EE/512, 256, 0, stream>>>(ei, csrc2);
    k_fixup<<<FB, 1024, 0, stream>>>(csrc2, s_src, s_dst, tabc, cnt, s1p);
    k_s1red<<<NN/256, 256, 0, stream>>>(s1p, tabc, cnt, Db, invs1, uA);

    // uA holds uh1; steps t=2..10: even t -> uB, odd t -> uA, t=10 -> out
    const float* cur = uA;
    for (int t = 2; t <= 10; ++t){
        float* dst = (t == 10) ? out : ((t & 1) ? uA : uB);
        k_spmv<<<NN/8, 256, 0, stream>>>(cnt, tabc, cur, Db, FW, invs1, dst,
                                         (t == 7) ? 1 : 0, (t == 10) ? 1 : 0);
        cur = dst;
    }
}

// Round 12
// 100.481 us; speedup vs baseline: 1.0671x; 1.0671x over previous
//
#include <hip/hip_runtime.h>
#include <stdint.h>

#define NN 8192      // nodes
#define FF 512       // feature dim
#define HH 64        // hidden
#define CC 10        // classes
#define PAD 12       // padded channel stride (3x float4)
#define EE 262144    // edges
#define NTR 512      // train nodes
#define ALPHA_NS 0.2f

#define CAP 96u              // slots per dst row (Poisson(32); P(deg>96) ~ e^-38)
#define EMPTY 0xFFFFFFFFu
#define ROWS_PB 32           // rows per k_init block
#define SLOTS_PB ((NN*CAP)/256u)   // 3072 csrc2 slots cleared per k_init block
#define FB 64                // fixup blocks

__device__ __forceinline__ float dot4(float4 a, float4 b){
    return a.x*b.x + a.y*b.y + a.z*b.z + a.w*b.w;
}

// ---------------------------------------------------------------------------
// k_init: per-block independent. Clears csrc2 slice (uint4), computes v01
// redundantly in LDS, s_src/s_dst/FW for its 32 rows, local cvec, padded Db
// and Db7 = Db + FW (pads zeroed in both).
// ---------------------------------------------------------------------------
__global__ __launch_bounds__(1024) void k_init(
    const float* __restrict__ W, const float* __restrict__ a,
    const float* __restrict__ h, const float* __restrict__ feat,
    const float* __restrict__ W1, const int* __restrict__ idx_tr,
    const int* __restrict__ labels,
    uint32_t* __restrict__ csrc2,
    float* __restrict__ s_src, float* __restrict__ s_dst,
    float* __restrict__ FW, float* __restrict__ Db, float* __restrict__ Db7)
{
    __shared__ float v0l[FF];
    __shared__ float v1l[FF];
    __shared__ int chist[CC];
    __shared__ float cvecl[CC];
    __shared__ uint8_t lmark[ROWS_PB];

    const int tid = threadIdx.x;
    const int b   = blockIdx.x;
    const int rbase = b * ROWS_PB;

    {   // uint4 clear: 3072 slots = 768 uint4 per block
        uint4* c4 = (uint4*)(csrc2 + (uint32_t)b*SLOTS_PB);
        const uint4 ev = make_uint4(EMPTY, EMPTY, EMPTY, EMPTY);
        for (uint32_t i = tid; i < SLOTS_PB/4u; i += 1024) c4[i] = ev;
    }

    // v01 in LDS: threads 0..511 -> v0, 512..1023 -> v1
    {
        int f = tid & (FF-1);
        const float* av = (tid < FF) ? a : (a + HH);
        float acc = 0.f;
        for (int hh = 0; hh < HH; ++hh) acc += W[hh*FF + f] * av[hh];
        if (tid < FF) v0l[f] = acc; else v1l[f] = acc;
    }

    if (tid < ROWS_PB) lmark[tid] = 0;
    if (tid < CC) chist[tid] = 0;
    __syncthreads();
    if (tid < NTR){
        int node = idx_tr[tid];
        atomicAdd(&chist[labels[node]], 1);
        unsigned lr = (unsigned)(node - rbase);
        if (lr < (unsigned)ROWS_PB) lmark[lr] = 1;
    }
    __syncthreads();
    if (tid < CC) cvecl[tid] = (float)chist[tid] / (float)NTR;
    __syncthreads();

    // s-dots + FW: 16 waves x 2 rows
    {
        const int wid = tid >> 6, lane = tid & 63;
        const float4* v0 = (const float4*)v0l;
        const float4* v1 = (const float4*)v1l;
        #pragma unroll
        for (int rr = 0; rr < 2; ++rr){
            int row = rbase + wid*2 + rr;
            const float4* hr = (const float4*)(h + (size_t)row*FF);
            float4 x0 = hr[lane*2], x1 = hr[lane*2+1];
            float a0 = dot4(x0, v0[lane*2]) + dot4(x1, v0[lane*2+1]);
            float a1 = dot4(x0, v1[lane*2]) + dot4(x1, v1[lane*2+1]);
            #pragma unroll
            for (int off = 32; off >= 1; off >>= 1){
                a0 += __shfl_xor(a0, off);
                a1 += __shfl_xor(a1, off);
            }
            if (lane == 0){ s_src[row] = a0; s_dst[row] = a1; }

            const float4* fr = (const float4*)(feat + (size_t)row*FF);
            float4 f0 = fr[lane*2], f1 = fr[lane*2+1];
            float acc[CC];
            #pragma unroll
            for (int c = 0; c < CC; ++c){
                const float4* wr = (const float4*)(W1 + c*FF);
                acc[c] = dot4(f0, wr[lane*2]) + dot4(f1, wr[lane*2+1]);
            }
            #pragma unroll
            for (int c = 0; c < CC; ++c){
                float r = acc[c];
                #pragma unroll
                for (int off = 32; off >= 1; off >>= 1) r += __shfl_xor(r, off);
                acc[c] = r;
            }
            if (lane == 0){
                #pragma unroll
                for (int c = 0; c < CC; ++c) FW[row*PAD + c] = acc[c];
            }
        }
    }
    __syncthreads();   // FW (this block's rows) visible to Db7 phase below

    // padded Db and Db7 = Db + FW for this block's 32 rows (384 elements)
    if (tid < ROWS_PB*PAD){
        int il = tid / PAD, c = tid - il*PAD;
        int row = rbase + il;
        float v = 0.f, v7 = 0.f;
        if (c < CC){
            if (lmark[il]) v = ((labels[row] == c) ? 1.0f : 0.0f) - cvecl[c];
            v7 = v + FW[row*PAD + c];
        }
        Db[row*PAD + c]  = v;
        Db7[row*PAD + c] = v7;
    }
}

// ---------------------------------------------------------------------------
// k_build: pure CAS dedup+placement, one edge per thread (round-10 config).
// Key = src in the dst row's 96 slots. No value stores, no atomicAdds.
// ---------------------------------------------------------------------------
__global__ void k_build(const int* __restrict__ ei, uint32_t* __restrict__ csrc2)
{
    int k = blockIdx.x*256 + threadIdx.x;
    uint32_t src = (uint32_t)ei[k];
    uint32_t dst = (uint32_t)ei[EE + k];
    uint32_t base = dst * CAP;
    uint32_t p = (uint32_t)(((uint64_t)(src * 2654435761u) * CAP) >> 32);
    for (uint32_t it = 0; it < CAP; ++it){
        uint32_t prev = atomicCAS(&csrc2[base + p], EMPTY, src);
        if (prev == EMPTY || prev == src) break;   // placed, or duplicate -> drop
        p = (p + 1u == CAP) ? 0u : p + 1u;
    }
}

// ---------------------------------------------------------------------------
// k_fixup: 64 blocks x 1024 threads; 16-lane group per row, 2 rows per group.
// Compacts row slots into tabc while recomputing e = exp(leaky(s_src+s_dst)),
// accumulates s1 partials in LDS (no global atomics), writes cnt.
// ---------------------------------------------------------------------------
__global__ __launch_bounds__(1024) void k_fixup(
    const uint32_t* __restrict__ csrc2, const float* __restrict__ s_src,
    const float* __restrict__ s_dst, uint2* __restrict__ tabc,
    uint32_t* __restrict__ cnt, float* __restrict__ s1p)
{
    __shared__ float s1l[NN];    // 32 KB
    const int tid = threadIdx.x;
    const int b   = blockIdx.x;
    const int wid = tid >> 6, lane = tid & 63;
    const int g   = lane >> 4, l16 = lane & 15;

    for (int i = tid; i < NN; i += 1024) s1l[i] = 0.f;
    __syncthreads();

    #pragma unroll
    for (int rr = 0; rr < 2; ++rr){
        const int row = (((b*16 + wid)*4 + g)*2) + rr;   // 64*16*4*2 = 8192
        const uint32_t base = (uint32_t)row * CAP;
        const float sdst = s_dst[row];
        uint32_t running = 0;
        #pragma unroll
        for (int step = 0; step < 6; ++step){     // 6*16 = 96 = CAP
            uint32_t key = csrc2[base + step*16 + l16];
            bool valid = (key != EMPTY);
            uint64_t bal = __ballot(valid);
            uint32_t grp = (uint32_t)((bal >> (g*16)) & 0xFFFFull);
            uint32_t rank = (uint32_t)__popc(grp & ((1u << l16) - 1u));
            if (valid){
                float z = s_src[key] + sdst;
                z = (z >= 0.f) ? z : ALPHA_NS * z;
                float e = expf(z);
                tabc[base + running + rank] = make_uint2(key, __float_as_uint(e));
                atomicAdd(&s1l[key], e);          // LDS atomic
            }
            running += (uint32_t)__popc(grp);
        }
        if (l16 == 0) cnt[row] = running;
    }
    __syncthreads();
    for (int i = tid; i < NN; i += 1024) s1p[(size_t)b*NN + i] = s1l[i];
}

// ---------------------------------------------------------------------------
// k_s1red: thread per row. Reduce s1 partials; self-loop append for s1==0
// rows; write inv_s1 and uh1 = Db / s1 (padded).
// ---------------------------------------------------------------------------
__global__ __launch_bounds__(256) void k_s1red(
    const float* __restrict__ s1p, uint2* __restrict__ tabc,
    uint32_t* __restrict__ cnt, const float* __restrict__ Db,
    float* __restrict__ invs1, float* __restrict__ uh1)
{
    int row = blockIdx.x*256 + threadIdx.x;
    float s = 0.f;
    for (int b = 0; b < FB; ++b) s += s1p[(size_t)b*NN + row];
    if (s == 0.f){                       // zero out-degree -> self loop, e=1
        uint32_t c = cnt[row];
        tabc[(uint32_t)row*CAP + c] = make_uint2((uint32_t)row, __float_as_uint(1.0f));
        cnt[row] = c + 1u;
        s = 1.0f;
    }
    float inv = 1.0f / s;
    invs1[row] = inv;
    const float4* d4 = (const float4*)(Db + (size_t)row*PAD);
    float4* u4 = (float4*)(uh1 + (size_t)row*PAD);
    #pragma unroll
    for (int q = 0; q < 3; ++q){
        float4 v = d4[q];
        v.x *= inv; v.y *= inv; v.z *= inv; v.w *= inv;
        u4[q] = v;
    }
}

// ---------------------------------------------------------------------------
// k_spmv: 16-lane row groups (4 rows/wave, round-10 config), 3x float4
// gathers on 12-padded u-hat. acc = sum e * uh_in[src]; u = acc + dbp[row]
// (dbp = Db, or Db+FW at t=7); non-final: store uh = u * inv_s1 (padded);
// final: store u dense.
// ---------------------------------------------------------------------------
__global__ __launch_bounds__(256) void k_spmv(
    const uint32_t* __restrict__ cnt, const uint2* __restrict__ tabc,
    const float* __restrict__ uh_in, const float* __restrict__ dbp,
    const float* __restrict__ invs1, float* __restrict__ uout, int final_step)
{
    const int tid = threadIdx.x;
    const int wid = tid >> 6, lane = tid & 63;
    const int l16 = lane & 15;
    const int row = blockIdx.x*16 + wid*4 + (lane >> 4);   // 512 blocks
    const uint2* tp = tabc + (uint32_t)row * CAP;
    const uint32_t n = cnt[row];

    float acc[PAD];
    #pragma unroll
    for (int c = 0; c < PAD; ++c) acc[c] = 0.f;
    for (uint32_t p = (uint32_t)l16; p < n; p += 16u){
        uint2 v = tp[p];
        float w = __uint_as_float(v.y);
        const float4* u4 = (const float4*)(uh_in + (size_t)v.x*PAD);
        float4 u0 = u4[0], u1 = u4[1], u2 = u4[2];
        acc[0] += w*u0.x; acc[1] += w*u0.y; acc[2]  += w*u0.z; acc[3]  += w*u0.w;
        acc[4] += w*u1.x; acc[5] += w*u1.y; acc[6]  += w*u1.z; acc[7]  += w*u1.w;
        acc[8] += w*u2.x; acc[9] += w*u2.y; acc[10] += w*u2.z; acc[11] += w*u2.w;
    }
    #pragma unroll
    for (int c = 0; c < PAD; ++c){
        float r = acc[c];
        #pragma unroll
        for (int off = 8; off >= 1; off >>= 1) r += __shfl_xor(r, off, 16);
        acc[c] = r;
    }
    // lane l16 handles channel l16
    float v = acc[0];
    #pragma unroll
    for (int c = 1; c < PAD; ++c) v = (l16 == c) ? acc[c] : v;
    if (l16 < CC) v += dbp[row*PAD + l16];
    else          v = 0.f;
    if (final_step){
        if (l16 < CC) uout[(size_t)row*CC + l16] = v;
    } else {
        v *= invs1[row];
        if (l16 < PAD) uout[(size_t)row*PAD + l16] = v;
    }
}

extern "C" void kernel_launch(void* const* d_in, const int* in_sizes, int n_in,
                              void* d_out, int out_size, void* d_ws, size_t ws_size,
                              hipStream_t stream){
    const float* h    = (const float*)d_in[0];
    const float* W    = (const float*)d_in[1];
    const float* a    = (const float*)d_in[2];
    const float* W1   = (const float*)d_in[3];
    const float* feat = (const float*)d_in[4];
    const int* ei     = (const int*)d_in[5];
    const int* idx_tr = (const int*)d_in[6];
    const int* labels = (const int*)d_in[7];
    float* out = (float*)d_out;

    char* wsp = (char*)d_ws;
    auto alloc = [&](size_t bytes)->void*{
        void* p = (void*)wsp;
        wsp += (bytes + 255) & ~(size_t)255;
        return p;
    };
    uint32_t* csrc2 = (uint32_t*)alloc((size_t)NN*CAP*4);   // 3 MB
    uint2*    tabc  = (uint2*)   alloc((size_t)NN*CAP*8);   // 6 MB
    float*    s1p   = (float*)   alloc((size_t)FB*NN*4);    // 2 MB
    uint32_t* cnt   = (uint32_t*)alloc(NN*4);
    float*    invs1 = (float*)   alloc(NN*4);
    float*    s_src = (float*)   alloc(NN*4);
    float*    s_dst = (float*)   alloc(NN*4);
    float*    FW    = (float*)   alloc((size_t)NN*PAD*4);
    float*    Db    = (float*)   alloc((size_t)NN*PAD*4);
    float*    Db7   = (float*)   alloc((size_t)NN*PAD*4);
    float*    uA    = (float*)   alloc((size_t)NN*PAD*4);
    float*    uB    = (float*)   alloc((size_t)NN*PAD*4);

    k_init <<<256, 1024, 0, stream>>>(W, a, h, feat, W1, idx_tr, labels,
                                      csrc2, s_src, s_dst, FW, Db, Db7);
    k_build<<<EE/256, 256, 0, stream>>>(ei, csrc2);
    k_fixup<<<FB, 1024, 0, stream>>>(csrc2, s_src, s_dst, tabc, cnt, s1p);
    k_s1red<<<NN/256, 256, 0, stream>>>(s1p, tabc, cnt, Db, invs1, uA);

    // uA holds uh1; steps t=2..10: even t -> uB, odd t -> uA, t=10 -> out
    const float* cur = uA;
    for (int t = 2; t <= 10; ++t){
        float* dst = (t == 10) ? out : ((t & 1) ? uA : uB);
        const float* dbp = (t == 7) ? Db7 : Db;
        k_spmv<<<NN/16, 256, 0, stream>>>(cnt, tabc, cur, dbp, invs1, dst,
                                          (t == 10) ? 1 : 0);
        cur = dst;
    }
}